// Round 16
// baseline (2732.719 us; speedup 1.0000x reference)
//
#include <hip/hip_runtime.h>
#include <hip/hip_bf16.h>

#define T_TOK 8192
#define HDIM  1024
#define FDIM  4096
#define NEXP  8
#define RT_MAX 24        // row-tile capacity per expert (3072 rows; mean 2048, sigma~42)

typedef __attribute__((ext_vector_type(8))) short short8;
typedef __attribute__((ext_vector_type(4))) float f32x4;
typedef unsigned short u16;
typedef unsigned int   u32;

// ---------------- ws layout (bytes) ----------------
#define XB_OFF    0ull
#define YBUF_OFF  (XB_OFF   + 16777216ull)   // y bf16 partials: 2T*2*H*2 = 67MB
#define HBUF_OFF  (YBUF_OFF + 134217728ull)  // h bf16: 2T*F*2 = 134MB
#define CNT_OFF   (HBUF_OFF + 134217728ull)
#define TLIST_OFF (CNT_OFF  + 128ull)
#define WLIST_OFF (TLIST_OFF + 262144ull)    // wt1,wt2 (T floats), slot1,slot2 (T ints)
#define WS_NEED   (WLIST_OFF + 262144ull)

__device__ __forceinline__ u16 f2bf(float f) {           // RNE fp32 -> bf16
  u32 u = __float_as_uint(f);
  return (u16)((u + 0x7fffu + ((u >> 16) & 1u)) >> 16);
}
__device__ __forceinline__ float bf2f(u16 v) {
  return __uint_as_float((u32)v << 16);
}
__device__ __forceinline__ u32 cvt_pk(float lo, float hi) {  // [15:0]=bf16(lo), [31:16]=bf16(hi)
  u32 r;
  asm("v_cvt_pk_bf16_f32 %0, %1, %2" : "=v"(r) : "v"(lo), "v"(hi));
  return r;
}

__device__ __forceinline__ void gl_lds16(const void* g, void* l) {
  __builtin_amdgcn_global_load_lds(
      (const __attribute__((address_space(1))) void*)g,
      (__attribute__((address_space(3))) void*)l, 16, 0, 0);
}

// ---------------- router: logits, top-2, lists; fused x->bf16 (R14-proven) ----------------
__global__ __launch_bounds__(256) void router_kernel(
    const float* __restrict__ x, const float* __restrict__ gw,
    float* __restrict__ logits, u16* __restrict__ xb,
    int* __restrict__ counts, int* __restrict__ tlist,
    float* __restrict__ wt1, float* __restrict__ wt2,
    int* __restrict__ slot1, int* __restrict__ slot2) {
  const int wid = threadIdx.x >> 6, lane = threadIdx.x & 63;
  const int t = blockIdx.x * 4 + wid;
  const float* xr = x + (size_t)t * HDIM + lane * 16;
  float4 xv[4];
#pragma unroll
  for (int q = 0; q < 4; ++q) xv[q] = ((const float4*)xr)[q];

  u32 pk[8];
#pragma unroll
  for (int q = 0; q < 4; ++q) {
    pk[q * 2 + 0] = (u32)f2bf(xv[q].x) | ((u32)f2bf(xv[q].y) << 16);
    pk[q * 2 + 1] = (u32)f2bf(xv[q].z) | ((u32)f2bf(xv[q].w) << 16);
  }
  u32* xbo = (u32*)(xb + (size_t)t * HDIM + lane * 16);
  ((uint4*)xbo)[0] = make_uint4(pk[0], pk[1], pk[2], pk[3]);
  ((uint4*)xbo)[1] = make_uint4(pk[4], pk[5], pk[6], pk[7]);

  float lg[NEXP];
#pragma unroll
  for (int e = 0; e < NEXP; ++e) {
    const float4* g = (const float4*)(gw + (size_t)e * HDIM + lane * 16);
    float s = 0.f;
#pragma unroll
    for (int q = 0; q < 4; ++q) {
      float4 gv = g[q];
      s += xv[q].x * gv.x + xv[q].y * gv.y + xv[q].z * gv.z + xv[q].w * gv.w;
    }
#pragma unroll
    for (int off = 32; off > 0; off >>= 1) s += __shfl_xor(s, off, 64);
    lg[e] = s;
  }
  if (lane == 0) {
    float* lo = logits + (size_t)t * NEXP;
#pragma unroll
    for (int e = 0; e < NEXP; ++e) lo[e] = lg[e];
    float v1 = -1e30f, v2 = -1e30f; int i1 = 0, i2 = 0;
#pragma unroll
    for (int e = 0; e < NEXP; ++e) {
      float le = lg[e];
      if (le > v1)      { v2 = v1; i2 = i1; v1 = le; i1 = e; }
      else if (le > v2) { v2 = le; i2 = e; }
    }
    float t2 = __expf(v2 - v1);
    float rs = 1.f / (1.f + t2);
    int p1 = atomicAdd(&counts[i1], 1);
    tlist[i1 * T_TOK + p1] = t;
    slot1[t] = (i1 << 16) | p1;  wt1[t] = rs;
    int p2 = atomicAdd(&counts[i2], 1);
    tlist[i2 * T_TOK + p2] = t;
    slot2[t] = (i2 << 16) | p2;  wt2[t] = t2 * rs;
  }
}

// ---------------- FFN1: 128x64 dual-B; B fp32 -> reg (1-step prefetch) -> cvt -> LDS ----------------
// A: gl_lds16 (proven). B loads for step k+1 issued before step-k's vmcnt-drain barrier,
// so their latency merges into the existing drain (wait = max, not sum).
__global__ __launch_bounds__(256, 4) void ffn1_kernel(
    const u16* __restrict__ xb, const float* __restrict__ w1, const float* __restrict__ w3,
    u16* __restrict__ hbuf, const int* __restrict__ counts, const int* __restrict__ tlist) {
  const int bid = blockIdx.x;
  const int e  = bid & 7;          // expert == XCD (L2 locality)
  const int j  = bid >> 3;
  const int ct = j / RT_MAX;       // F col tile 0..63 (64 wide)
  const int rt = j - ct * RT_MAX;  // row tile fastest -> B panel L2-resident
  const int Ne = counts[e];
  if (rt * 128 >= Ne) return;
  int hb = 0;
#pragma unroll
  for (int i = 0; i < NEXP; ++i) hb += (i < e) ? counts[i] : 0;

  __shared__ u16 LDS[16384];       // A @0 (16KB), B1 @8192 (8KB), B3 @12288 (8KB)

  const int tid = threadIdx.x;
  const int wid = tid >> 6, lane = tid & 63;
  const int wr = wid >> 1, wc = wid & 1;     // 2M x 2N, wave tile 64x32
  const int lr = lane & 15, lhi = lane >> 4;

  // A staging (source pre-swizzled for linear gl_lds16 dest — rule #21)
  size_t aoff[4];
#pragma unroll
  for (int q = 0; q < 4; ++q) {
    int idx = q * 256 + tid;
    int r = idx >> 3, c = idx & 7;
    int grow = rt * 128 + r;
    int gi = grow < Ne ? grow : Ne - 1;
    aoff[q] = (size_t)tlist[e * T_TOK + gi] * HDIM + (size_t)((c ^ (r & 7)) * 8);
  }
  const int dW = wid * 512;        // wave-uniform (u16); HW adds lane*16B

  // B fp32: slot s = q*256+tid; row r = s>>4 (0..63), fp32 chunk c32 = s&15.
  // Linear global read; swizzle on the ds_write side (R14-proven mapping, 0 conflicts).
  size_t boff[4]; int woff[4];
#pragma unroll
  for (int q = 0; q < 4; ++q) {
    int s = q * 256 + tid;
    int r = s >> 4, c32 = s & 15;
    boff[q] = ((size_t)e * FDIM + ct * 64 + r) * HDIM + c32 * 4;
    woff[q] = r * 64 + (((c32 >> 1) ^ (r & 7)) * 8) + (c32 & 1) * 4;   // u16 units
  }

  f32x4 acc1[4][2] = {}, acc3[4][2] = {};

  float4 v1[4], v3[4];             // prologue: B(k0=0)
#pragma unroll
  for (int q = 0; q < 4; ++q) v1[q] = *(const float4*)(w1 + boff[q]);
#pragma unroll
  for (int q = 0; q < 4; ++q) v3[q] = *(const float4*)(w3 + boff[q]);

  for (int k0 = 0; k0 < HDIM; k0 += 64) {
    __syncthreads();               // prev-step LDS readers done
#pragma unroll
    for (int q = 0; q < 4; ++q)
      gl_lds16(xb + aoff[q] + k0, LDS + q * 2048 + dW);
#pragma unroll
    for (int q = 0; q < 4; ++q) {  // write B(k0) from regs (loaded last step)
      uint2 p1; p1.x = cvt_pk(v1[q].x, v1[q].y); p1.y = cvt_pk(v1[q].z, v1[q].w);
      *(uint2*)(LDS + 8192 + woff[q]) = p1;
      uint2 p3; p3.x = cvt_pk(v3[q].x, v3[q].y); p3.y = cvt_pk(v3[q].z, v3[q].w);
      *(uint2*)(LDS + 12288 + woff[q]) = p3;
    }
    if (k0 + 64 < HDIM) {          // prefetch B(k0+64): drains with A at the barrier below
#pragma unroll
      for (int q = 0; q < 4; ++q) v1[q] = *(const float4*)(w1 + boff[q] + k0 + 64);
#pragma unroll
      for (int q = 0; q < 4; ++q) v3[q] = *(const float4*)(w3 + boff[q] + k0 + 64);
    }
    __syncthreads();               // A gl_lds16 + B prefetch drain together; ds_writes visible
#pragma unroll
    for (int kk = 0; kk < 2; ++kk) {
      const int chn = ((kk * 4 + lhi) ^ (lr & 7)) * 8;
      short8 af[4], b1f[2], b3f[2];
#pragma unroll
      for (int m = 0; m < 4; ++m)
        af[m] = *(const short8*)(LDS + (wr * 64 + m * 16 + lr) * 64 + chn);
#pragma unroll
      for (int n = 0; n < 2; ++n) {
        int ro = (wc * 32 + n * 16 + lr) * 64 + chn;
        b1f[n] = *(const short8*)(LDS + 8192 + ro);
        b3f[n] = *(const short8*)(LDS + 12288 + ro);
      }
#pragma unroll
      for (int m = 0; m < 4; ++m)
#pragma unroll
        for (int n = 0; n < 2; ++n) {
          acc1[m][n] = __builtin_amdgcn_mfma_f32_16x16x32_bf16(af[m], b1f[n], acc1[m][n], 0, 0, 0);
          acc3[m][n] = __builtin_amdgcn_mfma_f32_16x16x32_bf16(af[m], b3f[n], acc3[m][n], 0, 0, 0);
        }
    }
  }

  const int rbase = rt * 128 + wr * 64 + lhi * 4;
  const int cbase = ct * 64 + wc * 32 + lr;
#pragma unroll
  for (int m = 0; m < 4; ++m)
#pragma unroll
    for (int i = 0; i < 4; ++i) {
      int grow = rbase + m * 16 + i;
      if (grow < Ne) {
        size_t rowp = (size_t)(hb + grow) * FDIM + cbase;
#pragma unroll
        for (int n = 0; n < 2; ++n) {
          float a1 = acc1[m][n][i], a3 = acc3[m][n][i];
          hbuf[rowp + n * 16] = f2bf((a1 / (1.f + __expf(-a1))) * a3);
        }
      }
    }
}

// ---------------- FFN2: K-split 2, 128x128; w2 fp32 -> reg prefetch -> cvt -> LDS ----------------
__global__ __launch_bounds__(256, 4) void ffn2_kernel(
    const u16* __restrict__ hbuf, const float* __restrict__ w2,
    u16* __restrict__ ybuf, const int* __restrict__ counts) {
  const int bid = blockIdx.x;
  const int e  = bid & 7;
  const int j  = bid >> 3;
  const int rt = j % RT_MAX;       // row tile fastest
  const int rest = j / RT_MAX;
  const int ks = rest & 1;         // K half
  const int ct = rest >> 1;        // H col tile 0..7
  const int Ne = counts[e];
  if (rt * 128 >= Ne) return;
  int hb = 0;
#pragma unroll
  for (int i = 0; i < NEXP; ++i) hb += (i < e) ? counts[i] : 0;
  const int kbase = ks * 2048;

  __shared__ u16 Alds[128 * 64];
  __shared__ u16 Blds[128 * 64];

  const int tid = threadIdx.x;
  const int wid = tid >> 6, lane = tid & 63;
  const int wr = wid >> 1, wc = wid & 1;     // 2x2 waves, 64x64/wave
  const int lr = lane & 15, lhi = lane >> 4;

  size_t aoff[4]; int ldso[4];
#pragma unroll
  for (int q = 0; q < 4; ++q) {
    int i = wid * 4 + q;
    int r = i * 8 + (lane >> 3);
    int sw = ((lane & 7) ^ (r & 7)) * 8;
    int grow = rt * 128 + r;
    int gi = grow < Ne ? grow : Ne - 1;
    aoff[q] = (size_t)(hb + gi) * FDIM + kbase + sw;
    ldso[q] = i * 512;
  }
  // B fp32: slot s = q*256+tid; r = s>>4 (0..127), c32 = s&15
  size_t boff[8]; int woff[8];
#pragma unroll
  for (int q = 0; q < 8; ++q) {
    int s = q * 256 + tid;
    int r = s >> 4, c32 = s & 15;
    boff[q] = ((size_t)e * HDIM + ct * 128 + r) * FDIM + kbase + c32 * 4;
    woff[q] = r * 64 + (((c32 >> 1) ^ (r & 7)) * 8) + (c32 & 1) * 4;
  }

  f32x4 acc[4][4] = {};

  float4 v[8];
#pragma unroll
  for (int q = 0; q < 8; ++q) v[q] = *(const float4*)(w2 + boff[q]);

  for (int k0 = 0; k0 < 2048; k0 += 64) {
    __syncthreads();
#pragma unroll
    for (int q = 0; q < 4; ++q)
      gl_lds16(hbuf + aoff[q] + k0, Alds + ldso[q]);
#pragma unroll
    for (int q = 0; q < 8; ++q) {
      uint2 p; p.x = cvt_pk(v[q].x, v[q].y); p.y = cvt_pk(v[q].z, v[q].w);
      *(uint2*)(Blds + woff[q]) = p;
    }
    if (k0 + 64 < 2048) {
#pragma unroll
      for (int q = 0; q < 8; ++q) v[q] = *(const float4*)(w2 + boff[q] + k0 + 64);
    }
    __syncthreads();
#pragma unroll
    for (int kk = 0; kk < 2; ++kk) {
      const int swo = ((kk * 4 + lhi) ^ (lr & 7)) * 8;
      short8 af[4], bf_[4];
#pragma unroll
      for (int m = 0; m < 4; ++m)
        af[m] = *(const short8*)(Alds + (wr * 64 + m * 16 + lr) * 64 + swo);
#pragma unroll
      for (int n = 0; n < 4; ++n)
        bf_[n] = *(const short8*)(Blds + (wc * 64 + n * 16 + lr) * 64 + swo);
#pragma unroll
      for (int m = 0; m < 4; ++m)
#pragma unroll
        for (int n = 0; n < 4; ++n)
          acc[m][n] = __builtin_amdgcn_mfma_f32_16x16x32_bf16(af[m], bf_[n], acc[m][n], 0, 0, 0);
    }
  }

  const int rb = rt * 128 + wr * 64 + lhi * 4;
  const int cb = ct * 128 + wc * 64 + lr;
#pragma unroll
  for (int m = 0; m < 4; ++m)
#pragma unroll
    for (int i = 0; i < 4; ++i) {
      int grow = rb + m * 16 + i;
      if (grow < Ne) {
        u16* yp = ybuf + ((size_t)(hb + grow) * 2 + ks) * HDIM + cb;
#pragma unroll
        for (int n = 0; n < 4; ++n)
          yp[n * 16] = f2bf(acc[m][n][i]);
      }
    }
}

// ---------------- combine: out[t] = wt1*(y1a+y1b) + wt2*(y2a+y2b) ----------------
__global__ __launch_bounds__(256) void combine_kernel(
    const u16* __restrict__ ybuf, const int* __restrict__ slot1, const int* __restrict__ slot2,
    const float* __restrict__ wt1, const float* __restrict__ wt2,
    const int* __restrict__ counts, float* __restrict__ out) {
  int pre[NEXP + 1];
  pre[0] = 0;
#pragma unroll
  for (int i = 0; i < NEXP; ++i) pre[i + 1] = pre[i] + counts[i];
  int idx = blockIdx.x * 256 + threadIdx.x;    // T*128 threads, 8 cols each
  int t = idx >> 7, c8 = (idx & 127) * 8;
  int s1 = slot1[t], s2 = slot2[t];
  float w1 = wt1[t], w2 = wt2[t];
  size_t r1 = (size_t)(pre[s1 >> 16] + (s1 & 0xFFFF)) * 2 * HDIM + c8;
  size_t r2 = (size_t)(pre[s2 >> 16] + (s2 & 0xFFFF)) * 2 * HDIM + c8;
  short8 y1a = *(const short8*)(ybuf + r1);
  short8 y1b = *(const short8*)(ybuf + r1 + HDIM);
  short8 y2a = *(const short8*)(ybuf + r2);
  short8 y2b = *(const short8*)(ybuf + r2 + HDIM);
  float* op = out + (size_t)t * HDIM + c8;
#pragma unroll
  for (int k = 0; k < 8; ++k)
    op[k] = w1 * (bf2f((u16)y1a[k]) + bf2f((u16)y1b[k]))
          + w2 * (bf2f((u16)y2a[k]) + bf2f((u16)y2b[k]));
}

extern "C" void kernel_launch(void* const* d_in, const int* in_sizes, int n_in,
                              void* d_out, int out_size, void* d_ws, size_t ws_size,
                              hipStream_t stream) {
  (void)in_sizes; (void)n_in; (void)out_size;
  if (ws_size < WS_NEED) return;

  const float* x  = (const float*)d_in[0];
  const float* gw = (const float*)d_in[1];
  const float* w1 = (const float*)d_in[2];
  const float* w3 = (const float*)d_in[3];
  const float* w2 = (const float*)d_in[4];
  float* out = (float*)d_out;
  float* logits = out + (size_t)T_TOK * HDIM;

  char* ws = (char*)d_ws;
  u16* xb    = (u16*)(ws + XB_OFF);
  u16* ybuf  = (u16*)(ws + YBUF_OFF);
  u16* hbuf  = (u16*)(ws + HBUF_OFF);
  int* counts = (int*)(ws + CNT_OFF);
  int* tlist  = (int*)(ws + TLIST_OFF);
  float* wt1  = (float*)(ws + WLIST_OFF);
  float* wt2  = wt1 + T_TOK;
  int* slot1  = (int*)(wt2 + T_TOK);
  int* slot2  = slot1 + T_TOK;

  hipMemsetAsync(counts, 0, NEXP * sizeof(int), stream);

  router_kernel<<<T_TOK / 4, 256, 0, stream>>>(x, gw, logits, xb, counts, tlist,
                                               wt1, wt2, slot1, slot2);
  ffn1_kernel<<<NEXP * RT_MAX * 64, 256, 0, stream>>>(xb, w1, w3, hbuf, counts, tlist);
  ffn2_kernel<<<NEXP * RT_MAX * 8 * 2, 256, 0, stream>>>(hbuf, w2, ybuf, counts);
  combine_kernel<<<T_TOK * 128 / 256, 256, 0, stream>>>(ybuf, slot1, slot2, wt1, wt2, counts, out);
}

// Round 17
// 762.978 us; speedup vs baseline: 3.5816x; 3.5816x over previous
//
#include <hip/hip_runtime.h>
#include <hip/hip_bf16.h>

#define T_TOK 8192
#define HDIM  1024
#define FDIM  4096
#define NEXP  8
#define CVT_BLKS 2048
#define RT_MAX 24        // row-tile capacity per expert (3072 rows; mean 2048, sigma~42)

typedef __attribute__((ext_vector_type(8))) short short8;
typedef __attribute__((ext_vector_type(4))) float f32x4;
typedef unsigned short u16;
typedef unsigned int   u32;

// ---------------- ws layout (bytes) ----------------
#define XB_OFF    0ull
#define W1B_OFF   (XB_OFF   + 16777216ull)   // w1 bf16; W1B+W3B REUSED as ybuf (134MB) after ffn1
#define W3B_OFF   (W1B_OFF  + 67108864ull)
#define W2B_OFF   (W3B_OFF  + 67108864ull)
#define HBUF_OFF  (W2B_OFF  + 67108864ull)
#define CNT_OFF   (HBUF_OFF + 134217728ull)
#define TLIST_OFF (CNT_OFF  + 128ull)
#define WLIST_OFF (TLIST_OFF + 262144ull)    // wt1,wt2 (T floats), slot1,slot2 (T ints)
#define WS_NEED   (WLIST_OFF + 262144ull)

__device__ __forceinline__ u16 f2bf(float f) {           // RNE fp32 -> bf16
  u32 u = __float_as_uint(f);
  return (u16)((u + 0x7fffu + ((u >> 16) & 1u)) >> 16);
}
__device__ __forceinline__ float bf2f(u16 v) {
  return __uint_as_float((u32)v << 16);
}

__device__ __forceinline__ void gl_lds16(const void* g, void* l) {
  __builtin_amdgcn_global_load_lds(
      (const __attribute__((address_space(1))) void*)g,
      (__attribute__((address_space(3))) void*)l, 16, 0, 0);
}

// ---------------- prep: w1/w3 convert (blocks 0..8191) + router (8192..10239) ----------------
__global__ __launch_bounds__(256) void prep_kernel(
    const float* __restrict__ x, const float* __restrict__ gw,
    const float* __restrict__ s0, const float* __restrict__ s1,
    u16* __restrict__ d0, u16* __restrict__ d1,
    float* __restrict__ logits, u16* __restrict__ xb,
    int* __restrict__ counts, int* __restrict__ tlist,
    float* __restrict__ wt1, float* __restrict__ wt2,
    int* __restrict__ slot1, int* __restrict__ slot2) {
  if (blockIdx.x < 8192) {
    const int n8 = NEXP * FDIM * HDIM / 8;      // 2^22 per tensor
    const int total = 2 * n8;
    const int stride = 8192 * 256;
    for (int i = blockIdx.x * 256 + threadIdx.x; i < total; i += stride) {
      int seg = i >> 22;
      int j = i & (n8 - 1);
      const float* s = seg == 0 ? s0 : s1;
      u16* d = seg == 0 ? d0 : d1;
      float4 v0 = ((const float4*)s)[j * 2];
      float4 v1 = ((const float4*)s)[j * 2 + 1];
      uint4 o;
      o.x = (u32)f2bf(v0.x) | ((u32)f2bf(v0.y) << 16);
      o.y = (u32)f2bf(v0.z) | ((u32)f2bf(v0.w) << 16);
      o.z = (u32)f2bf(v1.x) | ((u32)f2bf(v1.y) << 16);
      o.w = (u32)f2bf(v1.z) | ((u32)f2bf(v1.w) << 16);
      ((uint4*)d)[j] = o;
    }
    return;
  }
  // ---- router: one wave per token ----
  const int wid = threadIdx.x >> 6, lane = threadIdx.x & 63;
  const int t = (blockIdx.x - 8192) * 4 + wid;
  const float* xr = x + (size_t)t * HDIM + lane * 16;
  float4 xv[4];
#pragma unroll
  for (int q = 0; q < 4; ++q) xv[q] = ((const float4*)xr)[q];

  u32 pk[8];
#pragma unroll
  for (int q = 0; q < 4; ++q) {
    pk[q * 2 + 0] = (u32)f2bf(xv[q].x) | ((u32)f2bf(xv[q].y) << 16);
    pk[q * 2 + 1] = (u32)f2bf(xv[q].z) | ((u32)f2bf(xv[q].w) << 16);
  }
  u32* xbo = (u32*)(xb + (size_t)t * HDIM + lane * 16);
  ((uint4*)xbo)[0] = make_uint4(pk[0], pk[1], pk[2], pk[3]);
  ((uint4*)xbo)[1] = make_uint4(pk[4], pk[5], pk[6], pk[7]);

  float lg[NEXP];
#pragma unroll
  for (int e = 0; e < NEXP; ++e) {
    const float4* g = (const float4*)(gw + (size_t)e * HDIM + lane * 16);
    float s = 0.f;
#pragma unroll
    for (int q = 0; q < 4; ++q) {
      float4 gv = g[q];
      s += xv[q].x * gv.x + xv[q].y * gv.y + xv[q].z * gv.z + xv[q].w * gv.w;
    }
#pragma unroll
    for (int off = 32; off > 0; off >>= 1) s += __shfl_xor(s, off, 64);
    lg[e] = s;
  }
  if (lane == 0) {
    float* lo = logits + (size_t)t * NEXP;
#pragma unroll
    for (int e = 0; e < NEXP; ++e) lo[e] = lg[e];
    float v1 = -1e30f, v2 = -1e30f; int i1 = 0, i2 = 0;
#pragma unroll
    for (int e = 0; e < NEXP; ++e) {
      float le = lg[e];
      if (le > v1)      { v2 = v1; i2 = i1; v1 = le; i1 = e; }
      else if (le > v2) { v2 = le; i2 = e; }
    }
    float t2 = __expf(v2 - v1);
    float rs = 1.f / (1.f + t2);
    int p1 = atomicAdd(&counts[i1], 1);
    tlist[i1 * T_TOK + p1] = t;
    slot1[t] = (i1 << 16) | p1;  wt1[t] = rs;
    int p2 = atomicAdd(&counts[i2], 1);
    tlist[i2 * T_TOK + p2] = t;
    slot2[t] = (i2 << 16) | p2;  wt2[t] = t2 * rs;
  }
}

// ---------------- FFN1: 128x64 dual-B tile, 256 thr, 32KB LDS (R7/R13-proven) ----------------
// First CVT_BLKS blocks convert w2 fp32->bf16 (overlaps with GEMM compute).
__global__ __launch_bounds__(256, 4) void ffn1_kernel(
    const u16* __restrict__ xb, const u16* __restrict__ w1b, const u16* __restrict__ w3b,
    u16* __restrict__ hbuf, const int* __restrict__ counts, const int* __restrict__ tlist,
    const float* __restrict__ w2src, u16* __restrict__ w2b) {
  if (blockIdx.x < CVT_BLKS) {
    const int n8 = NEXP * HDIM * FDIM / 8;      // 2^22
    const int stride = CVT_BLKS * 256;
    for (int j = blockIdx.x * 256 + threadIdx.x; j < n8; j += stride) {
      float4 v0 = ((const float4*)w2src)[j * 2];
      float4 v1 = ((const float4*)w2src)[j * 2 + 1];
      uint4 o;
      o.x = (u32)f2bf(v0.x) | ((u32)f2bf(v0.y) << 16);
      o.y = (u32)f2bf(v0.z) | ((u32)f2bf(v0.w) << 16);
      o.z = (u32)f2bf(v1.x) | ((u32)f2bf(v1.y) << 16);
      o.w = (u32)f2bf(v1.z) | ((u32)f2bf(v1.w) << 16);
      ((uint4*)w2b)[j] = o;
    }
    return;
  }
  const int bid = blockIdx.x - CVT_BLKS;
  const int e  = bid & 7;          // expert == XCD (L2 locality)
  const int j  = bid >> 3;         // 0..RT_MAX*64-1
  const int ct = j / RT_MAX;       // F col tile 0..63 (64 wide)
  const int rt = j - ct * RT_MAX;  // row tile fastest -> B panel L2-resident
  const int Ne = counts[e];
  if (rt * 128 >= Ne) return;
  int hb = 0;
#pragma unroll
  for (int i = 0; i < NEXP; ++i) hb += (i < e) ? counts[i] : 0;

  __shared__ u16 LDS[16384];       // A @0 (16KB), B1 @8192 (8KB), B3 @12288 (8KB)

  const int tid = threadIdx.x;
  const int wid = tid >> 6, lane = tid & 63;
  const int wr = wid >> 1, wc = wid & 1;     // 2M x 2N, wave tile 64x32
  const int lr = lane & 15, lhi = lane >> 4;

  size_t aoff[4];
#pragma unroll
  for (int q = 0; q < 4; ++q) {
    int idx = q * 256 + tid;
    int r = idx >> 3, c = idx & 7;
    int grow = rt * 128 + r;
    int gi = grow < Ne ? grow : Ne - 1;
    aoff[q] = (size_t)tlist[e * T_TOK + gi] * HDIM + (size_t)((c ^ (r & 7)) * 8);
  }
  size_t boff[2];
#pragma unroll
  for (int q = 0; q < 2; ++q) {
    int idx = q * 256 + tid;
    int r = idx >> 3, c = idx & 7;
    boff[q] = ((size_t)e * FDIM + ct * 64 + r) * HDIM + (size_t)((c ^ (r & 7)) * 8);
  }
  const int dW = wid * 64 * 8;     // wave-uniform (u16); HW adds lane*16B

  f32x4 acc1[4][2] = {}, acc3[4][2] = {};

  for (int k0 = 0; k0 < HDIM; k0 += 64) {
    __syncthreads();
#pragma unroll
    for (int q = 0; q < 4; ++q)
      gl_lds16(xb + aoff[q] + k0, LDS + q * 2048 + dW);
#pragma unroll
    for (int q = 0; q < 2; ++q) {
      gl_lds16(w1b + boff[q] + k0, LDS + 8192 + q * 2048 + dW);
      gl_lds16(w3b + boff[q] + k0, LDS + 12288 + q * 2048 + dW);
    }
    __syncthreads();
#pragma unroll
    for (int kk = 0; kk < 2; ++kk) {
      const int chn = ((kk * 4 + lhi) ^ (lr & 7)) * 8;
      short8 af[4], b1f[2], b3f[2];
#pragma unroll
      for (int m = 0; m < 4; ++m)
        af[m] = *(const short8*)(LDS + (wr * 64 + m * 16 + lr) * 64 + chn);
#pragma unroll
      for (int n = 0; n < 2; ++n) {
        int ro = (wc * 32 + n * 16 + lr) * 64 + chn;
        b1f[n] = *(const short8*)(LDS + 8192 + ro);
        b3f[n] = *(const short8*)(LDS + 12288 + ro);
      }
#pragma unroll
      for (int m = 0; m < 4; ++m)
#pragma unroll
        for (int n = 0; n < 2; ++n) {
          acc1[m][n] = __builtin_amdgcn_mfma_f32_16x16x32_bf16(af[m], b1f[n], acc1[m][n], 0, 0, 0);
          acc3[m][n] = __builtin_amdgcn_mfma_f32_16x16x32_bf16(af[m], b3f[n], acc3[m][n], 0, 0, 0);
        }
    }
  }

  const int rbase = rt * 128 + wr * 64 + lhi * 4;
  const int cbase = ct * 64 + wc * 32 + lr;
#pragma unroll
  for (int m = 0; m < 4; ++m)
#pragma unroll
    for (int i = 0; i < 4; ++i) {
      int grow = rbase + m * 16 + i;
      if (grow < Ne) {
        size_t rowp = (size_t)(hb + grow) * FDIM + cbase;
#pragma unroll
        for (int n = 0; n < 2; ++n) {
          float a1 = acc1[m][n][i], a3 = acc3[m][n][i];
          hbuf[rowp + n * 16] = f2bf((a1 / (1.f + __expf(-a1))) * a3);
        }
      }
    }
}

// ---------------- FFN2: K-split 2; y_partial[slot][ks] = h[:,ks] @ w2[:,ks]^T ----------------
// 128x128 tile, 4 waves (R9-proven inner loop); 3072 blocks -> 3 full occupancy rounds.
__global__ __launch_bounds__(256, 4) void ffn2_kernel(
    const u16* __restrict__ hbuf, const u16* __restrict__ w2b,
    u16* __restrict__ ybuf, const int* __restrict__ counts) {
  const int bid = blockIdx.x;
  const int e  = bid & 7;
  const int j  = bid >> 3;
  const int rt = j % RT_MAX;       // row tile fastest
  const int rest = j / RT_MAX;
  const int ks = rest & 1;         // K half
  const int ct = rest >> 1;        // H col tile 0..7
  const int Ne = counts[e];
  if (rt * 128 >= Ne) return;
  int hb = 0;
#pragma unroll
  for (int i = 0; i < NEXP; ++i) hb += (i < e) ? counts[i] : 0;
  const int kbase = ks * 2048;

  __shared__ u16 Alds[128 * 64];
  __shared__ u16 Blds[128 * 64];

  const int tid = threadIdx.x;
  const int wid = tid >> 6, lane = tid & 63;
  const int wr = wid >> 1, wc = wid & 1;     // 2x2 waves, 64x64/wave
  const int lr = lane & 15, lhi = lane >> 4;

  size_t aoff[4], boff[4]; int ldso[4];
#pragma unroll
  for (int q = 0; q < 4; ++q) {
    int i = wid * 4 + q;
    int r = i * 8 + (lane >> 3);
    int sw = ((lane & 7) ^ (r & 7)) * 8;
    int grow = rt * 128 + r;
    int gi = grow < Ne ? grow : Ne - 1;
    aoff[q] = (size_t)(hb + gi) * FDIM + kbase + sw;
    int hr = ct * 128 + r;
    boff[q] = ((size_t)e * HDIM + hr) * FDIM + kbase + sw;
    ldso[q] = i * 512;
  }

  f32x4 acc[4][4] = {};

  for (int k0 = 0; k0 < 2048; k0 += 64) {
    __syncthreads();
#pragma unroll
    for (int q = 0; q < 4; ++q) {
      gl_lds16(hbuf + aoff[q] + k0, Alds + ldso[q]);
      gl_lds16(w2b + boff[q] + k0, Blds + ldso[q]);
    }
    __syncthreads();
#pragma unroll
    for (int kk = 0; kk < 2; ++kk) {
      const int swo = ((kk * 4 + lhi) ^ (lr & 7)) * 8;
      short8 af[4], bf_[4];
#pragma unroll
      for (int m = 0; m < 4; ++m)
        af[m] = *(const short8*)(Alds + (wr * 64 + m * 16 + lr) * 64 + swo);
#pragma unroll
      for (int n = 0; n < 4; ++n)
        bf_[n] = *(const short8*)(Blds + (wc * 64 + n * 16 + lr) * 64 + swo);
#pragma unroll
      for (int m = 0; m < 4; ++m)
#pragma unroll
        for (int n = 0; n < 4; ++n)
          acc[m][n] = __builtin_amdgcn_mfma_f32_16x16x32_bf16(af[m], bf_[n], acc[m][n], 0, 0, 0);
    }
  }

  const int rb = rt * 128 + wr * 64 + lhi * 4;
  const int cb = ct * 128 + wc * 64 + lr;
#pragma unroll
  for (int m = 0; m < 4; ++m)
#pragma unroll
    for (int i = 0; i < 4; ++i) {
      int grow = rb + m * 16 + i;
      if (grow < Ne) {
        u16* yp = ybuf + ((size_t)(hb + grow) * 2 + ks) * HDIM + cb;
#pragma unroll
        for (int n = 0; n < 4; ++n)
          yp[n * 16] = f2bf(acc[m][n][i]);
      }
    }
}

// ---------------- combine: out[t] = wt1*(y1a+y1b) + wt2*(y2a+y2b) ----------------
__global__ __launch_bounds__(256) void combine_kernel(
    const u16* __restrict__ ybuf, const int* __restrict__ slot1, const int* __restrict__ slot2,
    const float* __restrict__ wt1, const float* __restrict__ wt2,
    const int* __restrict__ counts, float* __restrict__ out) {
  int pre[NEXP + 1];
  pre[0] = 0;
#pragma unroll
  for (int i = 0; i < NEXP; ++i) pre[i + 1] = pre[i] + counts[i];
  int idx = blockIdx.x * 256 + threadIdx.x;    // T*128 threads, 8 cols each
  int t = idx >> 7, c8 = (idx & 127) * 8;
  int s1 = slot1[t], s2 = slot2[t];
  float w1 = wt1[t], w2 = wt2[t];
  size_t r1 = (size_t)(pre[s1 >> 16] + (s1 & 0xFFFF)) * 2 * HDIM + c8;
  size_t r2 = (size_t)(pre[s2 >> 16] + (s2 & 0xFFFF)) * 2 * HDIM + c8;
  short8 y1a = *(const short8*)(ybuf + r1);
  short8 y1b = *(const short8*)(ybuf + r1 + HDIM);
  short8 y2a = *(const short8*)(ybuf + r2);
  short8 y2b = *(const short8*)(ybuf + r2 + HDIM);
  float* op = out + (size_t)t * HDIM + c8;
#pragma unroll
  for (int k = 0; k < 8; ++k)
    op[k] = w1 * (bf2f((u16)y1a[k]) + bf2f((u16)y1b[k]))
          + w2 * (bf2f((u16)y2a[k]) + bf2f((u16)y2b[k]));
}

extern "C" void kernel_launch(void* const* d_in, const int* in_sizes, int n_in,
                              void* d_out, int out_size, void* d_ws, size_t ws_size,
                              hipStream_t stream) {
  (void)in_sizes; (void)n_in; (void)out_size;
  if (ws_size < WS_NEED) return;

  const float* x  = (const float*)d_in[0];
  const float* gw = (const float*)d_in[1];
  const float* w1 = (const float*)d_in[2];
  const float* w3 = (const float*)d_in[3];
  const float* w2 = (const float*)d_in[4];
  float* out = (float*)d_out;
  float* logits = out + (size_t)T_TOK * HDIM;

  char* ws = (char*)d_ws;
  u16* xb    = (u16*)(ws + XB_OFF);
  u16* w1b   = (u16*)(ws + W1B_OFF);
  u16* w3b   = (u16*)(ws + W3B_OFF);
  u16* w2b   = (u16*)(ws + W2B_OFF);
  u16* hbuf  = (u16*)(ws + HBUF_OFF);
  u16* ybuf  = (u16*)(ws + W1B_OFF);   // alias: w1b+w3b (134MB) free after ffn1
  int* counts = (int*)(ws + CNT_OFF);
  int* tlist  = (int*)(ws + TLIST_OFF);
  float* wt1  = (float*)(ws + WLIST_OFF);
  float* wt2  = wt1 + T_TOK;
  int* slot1  = (int*)(wt2 + T_TOK);
  int* slot2  = slot1 + T_TOK;

  hipMemsetAsync(counts, 0, NEXP * sizeof(int), stream);

  prep_kernel<<<8192 + 2048, 256, 0, stream>>>(x, gw, w1, w3, w1b, w3b,
                                               logits, xb, counts, tlist,
                                               wt1, wt2, slot1, slot2);
  ffn1_kernel<<<CVT_BLKS + NEXP * RT_MAX * 64, 256, 0, stream>>>(
      xb, w1b, w3b, hbuf, counts, tlist, w2, w2b);
  ffn2_kernel<<<NEXP * RT_MAX * 8 * 2, 256, 0, stream>>>(hbuf, w2b, ybuf, counts);
  combine_kernel<<<T_TOK * 128 / 256, 256, 0, stream>>>(ybuf, slot1, slot2, wt1, wt2, counts, out);
}